// Round 6
// baseline (534.221 us; speedup 1.0000x reference)
//
#include <hip/hip_runtime.h>
#include <hip/hip_bf16.h>

typedef unsigned short u16;
typedef __attribute__((ext_vector_type(8))) short short8;   // 8 x bf16 = 4 VGPRs
typedef __attribute__((ext_vector_type(4))) float f32x4;

#define B_    4
#define L_    8192
#define C_    256
#define BL_   (B_*L_)
#define BLC_  (BL_*C_)
#define FFN_  2048
#define EPS_  1e-5f

#define GLDS(dst, src) __builtin_amdgcn_global_load_lds( \
    (const __attribute__((address_space(1))) unsigned int*)(src), \
    (__attribute__((address_space(3))) unsigned int*)(dst), 16, 0, 0)

__device__ __forceinline__ float bf2f(u16 v) {
  union { unsigned int u; float f; } x; x.u = ((unsigned int)v) << 16; return x.f;
}
__device__ __forceinline__ u16 f2bf(float f) {
  union { float f; unsigned int u; } x; x.f = f;
  unsigned int lsb = (x.u >> 16) & 1u;
  return (u16)((x.u + 0x7fffu + lsb) >> 16);
}
// GELU tanh-form: gelu(x) = x * (1 - 1/(1 + 2^(c1*x + c2*x^3)))
// c = sqrt(2/pi)*2*log2(e); max err ~1e-3 vs exact erf (post-LN ~6e-3, ok)
__device__ __forceinline__ float gelu_f(float x) {
  float u = x * x;
  float w = x * (2.3023879925f + 0.1029517046f * u);
  float e = exp2f(w);
  float r = __builtin_amdgcn_rcpf(1.f + e);
  return x - x * r;
}

// ---------------------------------------------------------------------------
// General GEMM: C[m,n] = act( sum_k A[m,k]*Bt[n,k] + bias[n] )
// m97 structure, 128x128 tile, BK=64, DMA quad-XOR swizzle.
// XCD supertile swizzle when mtiles%8==0: XCD x owns contiguous m-range,
// n fastest -> A slice stays L2-resident across n-sweeps.
// MODE 0: A=A0. MODE 1: K-concat at SEL. MODE 2: N-switch at SEL (QKV).
// ACT 1: gelu. SPLITK 1: fp32 atomicAdd into Cf, scaled by 1/bias[bz*N+col].
// ---------------------------------------------------------------------------
template<int MODE, int ACT, int SPLITK>
__launch_bounds__(256, 2)
__global__ void gemm_abt(const u16* __restrict__ A0, const u16* __restrict__ A1,
                         int SEL, int lda,
                         const u16* __restrict__ Bt,
                         const float* __restrict__ bias,
                         u16* __restrict__ Cb, float* __restrict__ Cf,
                         int M, int N, int K,
                         long sAb, long sBb, long sCb)
{
  __shared__ __align__(16) u16 As[2 * 128 * 32];
  __shared__ __align__(16) u16 Bs[2 * 128 * 32];

  const int mtiles = M >> 7, ntiles = N >> 7;
  const int tile = blockIdx.x;
  int mt0, nt0;
  if ((mtiles & 7) == 0) {
    const int x = tile & 7, g = tile >> 3;
    mt0 = ((x * (mtiles >> 3)) + g / ntiles) << 7;
    nt0 = (g % ntiles) << 7;
  } else {
    mt0 = (tile % mtiles) << 7;
    nt0 = (tile / mtiles) << 7;
  }
  const int kchunk = K / (int)gridDim.y;
  const int k0beg = blockIdx.y * kchunk;
  const int k0end = k0beg + kchunk;
  const int bz = blockIdx.z;
  A0 += (long)bz * sAb;  A1 += (long)bz * sAb;  Bt += (long)bz * sBb;

  const u16* Abase = (MODE == 2 && nt0 >= SEL) ? A1 : A0;

  const int tid  = threadIdx.x;
  const int wave = tid >> 6, lane = tid & 63;
  const int srow = lane >> 2;
  const int gq   = (lane & 3) ^ (srow & 3);
  const int frow = lane & 15;
  const int fq   = lane >> 4;
  const int fqx  = (fq ^ (frow & 3)) * 8;

  f32x4 zero = {0.f, 0.f, 0.f, 0.f};
  f32x4 acc[4][4];
#pragma unroll
  for (int i = 0; i < 4; i++)
#pragma unroll
    for (int j = 0; j < 4; j++) acc[i][j] = zero;

  const int wm = (wave & 1) * 64, wn = (wave >> 1) * 64;

  for (int k0 = k0beg; k0 < k0end; k0 += 64) {
    __syncthreads();
    const u16* Asrc;
    int ka;
    if (MODE == 1) {
      const bool lo = (k0 < SEL);
      Asrc = lo ? A0 : A1;
      ka = lo ? k0 : (k0 - SEL);
    } else { Asrc = Abase; ka = k0; }
#pragma unroll
    for (int h = 0; h < 2; h++) {
#pragma unroll
      for (int i = 0; i < 2; i++) {
        const int chunk = i * 4 + wave;
        GLDS(&As[h * 4096 + chunk * 512],
             Asrc + (long)(mt0 + chunk * 16 + srow) * lda + (ka + h * 32 + gq * 8));
        GLDS(&Bs[h * 4096 + chunk * 512],
             Bt + (long)(nt0 + chunk * 16 + srow) * K + (k0 + h * 32 + gq * 8));
      }
    }
    __syncthreads();
#pragma unroll
    for (int h = 0; h < 2; h++) {
      short8 af[4], bf[4];
#pragma unroll
      for (int t = 0; t < 4; t++)
        af[t] = *(const short8*)&As[h * 4096 + (wm + t * 16 + frow) * 32 + fqx];
#pragma unroll
      for (int t = 0; t < 4; t++)
        bf[t] = *(const short8*)&Bs[h * 4096 + (wn + t * 16 + frow) * 32 + fqx];
#pragma unroll
      for (int mt = 0; mt < 4; mt++)
#pragma unroll
        for (int nt = 0; nt < 4; nt++)
          acc[mt][nt] = __builtin_amdgcn_mfma_f32_16x16x32_bf16(af[mt], bf[nt], acc[mt][nt], 0, 0, 0);
    }
  }

  if (SPLITK) {
    float* Cp = Cf + (long)bz * sCb;
    float sv[4];
#pragma unroll
    for (int nt = 0; nt < 4; nt++)
      sv[nt] = bias ? (1.f / bias[(long)bz * N + nt0 + wn + nt * 16 + frow]) : 1.f;
#pragma unroll
    for (int mt = 0; mt < 4; mt++)
#pragma unroll
      for (int r = 0; r < 4; r++) {
        const int row = mt0 + wm + mt * 16 + fq * 4 + r;
#pragma unroll
        for (int nt = 0; nt < 4; nt++)
          atomicAdd(&Cp[(long)row * N + nt0 + wn + nt * 16 + frow],
                    acc[mt][nt][r] * sv[nt]);
      }
  } else {
    u16* Cp = Cb + (long)bz * sCb;
    float bv[4];
#pragma unroll
    for (int nt = 0; nt < 4; nt++)
      bv[nt] = bias ? bias[nt0 + wn + nt * 16 + frow] : 0.f;
#pragma unroll
    for (int mt = 0; mt < 4; mt++)
#pragma unroll
      for (int r = 0; r < 4; r++) {
        const int row = mt0 + wm + mt * 16 + fq * 4 + r;
#pragma unroll
        for (int nt = 0; nt < 4; nt++) {
          float v = acc[mt][nt][r] + bv[nt];
          if (ACT == 1) v = gelu_f(v);
          Cp[(long)row * N + nt0 + wn + nt * 16 + frow] = f2bf(v);
        }
      }
  }
}

// ---------------------------------------------------------------------------
// GEMM (M-tile 64, full N=256) + fused LayerNorm epilogue.
// CVTB=1: B operand is fp32 (converted during LDS staging).
// OUTF=0: out bf16 (message=LN1). OUTF=1: +bias, LN2, +fp32 src residual,
// fp32 out (final FFN2).  z = gm0 >> zshift selects batch for A/B strides.
// ---------------------------------------------------------------------------
template<int CVTB, int OUTF>
__launch_bounds__(256, 3)
__global__ void gemm_ln(const u16* __restrict__ A, long sAb, int lda, int K,
                        const void* __restrict__ Btv, long sBb, int zshift,
                        const float* __restrict__ bias,
                        const float* __restrict__ gamma, const float* __restrict__ beta,
                        const float* __restrict__ src, void* __restrict__ outv,
                        long Moff)
{
  __shared__ __align__(16) u16 As[2 * 64 * 32];    // 8 KB
  __shared__ __align__(16) u16 Bs[2 * 256 * 32];   // 32 KB
  __shared__ float red_s[64][4], red_q[64][4];

  const int gm0 = blockIdx.x * 64;
  const int z = gm0 >> zshift;
  const int ml = gm0 - (z << zshift);
  A += (long)z * sAb + (long)ml * lda;
  const float* Bf = (const float*)Btv + (CVTB ? (long)z * sBb : 0);
  const u16*   Bb = (const u16*)Btv   + (CVTB ? 0 : (long)z * sBb);

  const int tid = threadIdx.x, wave = tid >> 6, lane = tid & 63;
  const int srow = lane >> 2, gq = (lane & 3) ^ (srow & 3);
  const int frow = lane & 15, fq = lane >> 4;
  const int fqx = (fq ^ (frow & 3)) * 8;
  const int wn = wave * 64;

  f32x4 zero = {0.f, 0.f, 0.f, 0.f};
  f32x4 acc[4][4];
#pragma unroll
  for (int i = 0; i < 4; i++)
#pragma unroll
    for (int j = 0; j < 4; j++) acc[i][j] = zero;

  for (int k0 = 0; k0 < K; k0 += 64) {
    __syncthreads();
#pragma unroll
    for (int h = 0; h < 2; h++) {
      GLDS(&As[h * 2048 + wave * 512],
           A + (long)(wave * 16 + srow) * lda + (k0 + h * 32 + gq * 8));
#pragma unroll
      for (int i = 0; i < 4; i++) {
        const int chunk = i * 4 + wave;
        if (CVTB) {
          const float* bp = Bf + (long)(chunk * 16 + srow) * K + (k0 + h * 32 + gq * 8);
          float4 p0 = *(const float4*)bp;
          float4 p1 = *(const float4*)(bp + 4);
          short8 w;
          w[0] = (short)f2bf(p0.x); w[1] = (short)f2bf(p0.y);
          w[2] = (short)f2bf(p0.z); w[3] = (short)f2bf(p0.w);
          w[4] = (short)f2bf(p1.x); w[5] = (short)f2bf(p1.y);
          w[6] = (short)f2bf(p1.z); w[7] = (short)f2bf(p1.w);
          *(short8*)&Bs[h * 8192 + chunk * 512 + srow * 32 + (lane & 3) * 8] = w;
        } else {
          GLDS(&Bs[h * 8192 + chunk * 512],
               Bb + (long)(chunk * 16 + srow) * K + (k0 + h * 32 + gq * 8));
        }
      }
    }
    __syncthreads();
#pragma unroll
    for (int h = 0; h < 2; h++) {
      short8 af[4], bf[4];
#pragma unroll
      for (int t = 0; t < 4; t++)
        af[t] = *(const short8*)&As[h * 2048 + (t * 16 + frow) * 32 + fqx];
#pragma unroll
      for (int t = 0; t < 4; t++)
        bf[t] = *(const short8*)&Bs[h * 8192 + (wn + t * 16 + frow) * 32 + fqx];
#pragma unroll
      for (int mt = 0; mt < 4; mt++)
#pragma unroll
        for (int nt = 0; nt < 4; nt++)
          acc[mt][nt] = __builtin_amdgcn_mfma_f32_16x16x32_bf16(af[mt], bf[nt], acc[mt][nt], 0, 0, 0);
    }
  }

  // LN epilogue over the 256 cols of each of the 64 rows.
  float gv[4], bv[4], b2v[4];
#pragma unroll
  for (int nt = 0; nt < 4; nt++) {
    const int col = wn + nt * 16 + frow;
    gv[nt] = gamma[col]; bv[nt] = beta[col];
    b2v[nt] = OUTF ? bias[col] : 0.f;
  }
#pragma unroll
  for (int mt = 0; mt < 4; mt++)
#pragma unroll
    for (int r = 0; r < 4; r++) {
      float s = 0.f, q = 0.f;
#pragma unroll
      for (int nt = 0; nt < 4; nt++) {
        float v = acc[mt][nt][r] + b2v[nt];
        acc[mt][nt][r] = v; s += v; q += v * v;
      }
#pragma unroll
      for (int m = 1; m < 16; m <<= 1) {
        s += __shfl_xor(s, m, 16); q += __shfl_xor(q, m, 16);
      }
      if (frow == 0) {
        const int row = mt * 16 + fq * 4 + r;
        red_s[row][wave] = s; red_q[row][wave] = q;
      }
    }
  __syncthreads();
#pragma unroll
  for (int mt = 0; mt < 4; mt++)
#pragma unroll
    for (int r = 0; r < 4; r++) {
      const int row = mt * 16 + fq * 4 + r;
      float4 ss = *(const float4*)red_s[row];
      float4 qq = *(const float4*)red_q[row];
      const float s = ss.x + ss.y + ss.z + ss.w;
      const float q = qq.x + qq.y + qq.z + qq.w;
      const float mu = s * (1.f / 256.f);
      const float var = q * (1.f / 256.f) - mu * mu;
      const float rs = 1.f / sqrtf(var + EPS_);
      const long grow = Moff + gm0 + row;
#pragma unroll
      for (int nt = 0; nt < 4; nt++) {
        const int col = wn + nt * 16 + frow;
        const float o = (acc[mt][nt][r] - mu) * rs * gv[nt] + bv[nt];
        if (OUTF)
          ((float*)outv)[grow * 256 + col] = o + src[grow * 256 + col];
        else
          ((u16*)outv)[grow * 256 + col] = f2bf(o);
      }
    }
}

// ---------------------------------------------------------------------------
// All weight packing in one launch (1792 blocks of (32,8)).
// ---------------------------------------------------------------------------
__global__ void weightpack(const float* __restrict__ Wq, const float* __restrict__ Wk,
                           const float* __restrict__ Wv, const float* __restrict__ Wl,
                           const float* __restrict__ W1, const float* __restrict__ W2,
                           u16* __restrict__ WqC, u16* __restrict__ WlT,
                           u16* __restrict__ WqkvT, u16* __restrict__ W1T,
                           u16* __restrict__ W2T)
{
  __shared__ u16 t[32][33];
  const int bid = blockIdx.x, tx = threadIdx.x, ty = threadIdx.y;
  const float* in; u16* out; int Cc, R, bx, by;
  if (bid < 256) {
    const int w = bid >> 6, tt = bid & 63;
    bx = (tt & 7) * 32; by = (tt >> 3) * 32; Cc = 256; R = 256;
    if (w == 0) {
#pragma unroll
      for (int i = ty; i < 32; i += 8)
        WqC[(long)(by + i) * 256 + bx + tx] = f2bf(Wq[(long)(by + i) * 256 + bx + tx]);
      return;
    }
    in  = (w == 1) ? Wl : (w == 2) ? Wk : Wv;
    out = (w == 1) ? WlT : (w == 2) ? (WqkvT + 65536) : (WqkvT + 131072);
  } else if (bid < 1280) {
    const int l = bid - 256; bx = (l & 63) * 32; by = (l >> 6) * 32;
    in = W1; out = W1T; Cc = 2048; R = 512;
  } else {
    const int l = bid - 1280; bx = (l & 7) * 32; by = (l >> 3) * 32;
    in = W2; out = W2T; Cc = 256; R = 2048;
  }
#pragma unroll
  for (int i = ty; i < 32; i += 8)
    t[i][tx] = f2bf(in[(long)(by + i) * Cc + bx + tx]);
  __syncthreads();
#pragma unroll
  for (int i = ty; i < 32; i += 8)
    out[(long)(bx + i) * R + by + tx] = t[tx][i];
}

// cast source/target fp32->bf16 (grid.y selects) + zero Mtf||sexp (tail)
__global__ void castzero(const float* __restrict__ src, const float* __restrict__ tgt,
                         u16* __restrict__ srcB, u16* __restrict__ tgtB,
                         float* __restrict__ Mtf)
{
  const int x = blockIdx.x;
  if (x < BLC_ / 1024) {
    const float* in = blockIdx.y ? tgt : src;
    u16* out = blockIdx.y ? tgtB : srcB;
    const int i = (x * 256 + threadIdx.x) * 4;
    float4 v = *(const float4*)(in + i);
    ushort4 o; o.x = f2bf(v.x); o.y = f2bf(v.y); o.z = f2bf(v.z); o.w = f2bf(v.w);
    *(ushort4*)(out + i) = o;
  } else if (blockIdx.y == 0) {
    const int i = ((x - BLC_ / 1024) * 256 + threadIdx.x) * 4;
    float4 zv = {0.f, 0.f, 0.f, 0.f};
    *(float4*)(Mtf + i) = zv;   // covers Mtf (256K floats) + sexp (1K floats)
  }
}

// ql,k slices of QKV (B,L,768) -> (B,C,L). z<4: ql batches.
// z>=4: k batches with exp() applied and per-(b,e) column sums -> sexp.
__global__ void transQK(const u16* __restrict__ QKV,
                        u16* __restrict__ qlT, u16* __restrict__ kT,
                        float* __restrict__ sexp)
{
  __shared__ u16 t[32][33];
  const int z = blockIdx.z, zb = z & 3;
  const bool isk = (z >= 4);
  const u16* in = QKV + (long)zb * L_ * 768 + (isk ? 256 : 0);
  u16* out = (isk ? kT : qlT) + (long)zb * L_ * C_;
  const int bx = blockIdx.x * 32, by = blockIdx.y * 32;
  const int tx = threadIdx.x, ty = threadIdx.y;
#pragma unroll
  for (int i = ty; i < 32; i += 8)
    t[i][tx] = in[(long)(by + i) * 768 + bx + tx];
  __syncthreads();
  if (isk) {
#pragma unroll
    for (int i = ty; i < 32; i += 8) {
      float ex = __expf(bf2f(t[tx][i]));           // no max-sub: |k| small
      out[(long)(bx + i) * L_ + by + tx] = f2bf(ex);
      float ps = ex;
#pragma unroll
      for (int m = 1; m <= 16; m <<= 1) ps += __shfl_xor(ps, m, 32);
      if (tx == 0) atomicAdd(&sexp[(long)zb * C_ + bx + i], ps);
    }
  } else {
#pragma unroll
    for (int i = ty; i < 32; i += 8)
      out[(long)(bx + i) * L_ + by + tx] = t[tx][i];
  }
}

// ---------------------------------------------------------------------------
extern "C" void kernel_launch(void* const* d_in, const int* in_sizes, int n_in,
                              void* d_out, int out_size, void* d_ws, size_t ws_size,
                              hipStream_t stream)
{
  const float* source = (const float*)d_in[0];
  const float* target = (const float*)d_in[1];
  const float* Wq     = (const float*)d_in[2];
  const float* Wk     = (const float*)d_in[3];
  const float* Wv     = (const float*)d_in[4];
  const float* Wl     = (const float*)d_in[5];
  const float* gamma1 = (const float*)d_in[6];
  const float* beta1  = (const float*)d_in[7];
  const float* W1     = (const float*)d_in[8];
  const float* b1     = (const float*)d_in[9];
  const float* W2     = (const float*)d_in[10];
  const float* b2     = (const float*)d_in[11];
  const float* gamma2 = (const float*)d_in[12];
  const float* beta2  = (const float*)d_in[13];
  (void)in_sizes; (void)n_in; (void)out_size;

  char* ws = (char*)d_ws;
  size_t off = 0;
  auto take = [&](size_t bytes) -> char* {
    char* p = ws + off; off += (bytes + 255) & ~(size_t)255; return p;
  };
  // fixed region (live through FFN)
  u16*   WqkvT = (u16*)take((size_t)768 * C_ * 2);   // [ql|k|v] weights, NxK
  u16*   WqC   = (u16*)take((size_t)C_ * C_ * 2);    // Wq cast (d,e)
  u16*   WlT   = (u16*)take((size_t)C_ * C_ * 2);
  u16*   W1T   = (u16*)take((size_t)FFN_ * 512 * 2);
  u16*   W2T   = (u16*)take((size_t)C_ * FFN_ * 2);
  float* Mtf   = (float*)take((size_t)B_ * C_ * C_ * 4);
  float* sexp  = (float*)take((size_t)B_ * C_ * 4);  // contiguous after Mtf
  u16*   srcB  = (u16*)take((size_t)BLC_ * 2);
  u16*   msg   = (u16*)take((size_t)BLC_ * 2);
  const size_t ubase = off;
  // pool region (dead before FFN; hidden overlays it)
  u16*   tgtB  = (u16*)take((size_t)BLC_ * 2);
  u16*   QKV   = (u16*)take((size_t)BL_ * 768 * 2);
  u16*   qlT   = (u16*)take((size_t)BLC_ * 2);
  u16*   kT    = (u16*)take((size_t)BLC_ * 2);
  const size_t pool = off - ubase;
  u16*   hidden = (u16*)(ws + ubase);

  int nchunk = 1;
  for (; nchunk < 8; nchunk <<= 1) {
    size_t hid = ((size_t)BL_ / nchunk) * FFN_ * 2;
    size_t need = ubase + (hid > pool ? hid : pool);
    if (need <= ws_size) break;
  }
  const int Mc = BL_ / nchunk;

  dim3 tb(32, 8);
  weightpack<<<1792, tb, 0, stream>>>(Wq, Wk, Wv, Wl, W1, W2, WqC, WlT, WqkvT, W1T, W2T);
  castzero<<<dim3(BLC_ / 1024 + (B_ * C_ * C_ + B_ * C_) / 1024, 2), 256, 0, stream>>>(
      source, target, srcB, tgtB, Mtf);

  // Wql^T[c,d] = sum_e Wl[e,c] * Wq[d,e]  -> q-slot of WqkvT (tiny GEMM)
  gemm_abt<0,0,0><<<4, 256, 0, stream>>>(
      WlT, WlT, 0, C_, WqC, nullptr, WqkvT, nullptr, C_, C_, C_, 0, 0, 0);

  // [ql|k|v] = [src|tgt|tgt] @ [Wql|Wk|Wv]   (N-switch at 256)
  gemm_abt<2,0,0><<<(BL_/128)*(768/128), 256, 0, stream>>>(
      srcB, tgtB, 256, C_, WqkvT, nullptr, QKV, nullptr, BL_, 768, C_, 0, 0, 0);

  // ql transpose; k transpose+exp+colsum (softmax normalization deferred)
  transQK<<<dim3(8, L_/32, 8), tb, 0, stream>>>(QKV, qlT, kT, sexp);

  // Mt[c,e] = (sum_n qlT[c,n] * kexpT[e,n]) / sexp[e]  (split-K, fp32 atomics)
  gemm_abt<0,0,1><<<dim3(4, 16, B_), 256, 0, stream>>>(
      qlT, qlT, 0, L_, kT, sexp, nullptr, Mtf, C_, C_, L_,
      (long)C_*L_, (long)C_*L_, (long)C_*C_);

  // message = LN1( v @ Mt^T )   (v strided in QKV; Mt staged fp32->bf16)
  gemm_ln<1,0><<<BL_/64, 256, 0, stream>>>(
      QKV + 512, (long)L_*768, 768, 256, Mtf, (long)C_*C_, 13,
      nullptr, gamma1, beta1, nullptr, msg, 0);

  // FFN: hidden = gelu([src|msg]@W1+b1); out = src + LN2(hidden@W2+b2)
  for (int ch = 0; ch < nchunk; ch++) {
    const long moff = (long)ch * Mc;
    gemm_abt<1,1,0><<<(Mc/128)*(FFN_/128), 256, 0, stream>>>(
        srcB + moff * C_, msg + moff * C_, 256, C_, W1T, b1, hidden, nullptr,
        Mc, FFN_, 512, 0, 0, 0);
    gemm_ln<0,1><<<Mc/64, 256, 0, stream>>>(
        hidden, 0, FFN_, FFN_, W2T, 0, 30,
        b2, gamma2, beta2, source, d_out, moff);
  }
}

// Round 7
// 399.838 us; speedup vs baseline: 1.3361x; 1.3361x over previous
//
#include <hip/hip_runtime.h>
#include <hip/hip_bf16.h>

typedef unsigned short u16;
typedef __attribute__((ext_vector_type(8))) short short8;   // 8 x bf16 = 4 VGPRs
typedef __attribute__((ext_vector_type(4))) float f32x4;

#define B_    4
#define L_    8192
#define C_    256
#define BL_   (B_*L_)
#define BLC_  (BL_*C_)
#define FFN_  2048
#define EPS_  1e-5f

#define GLDS(dst, src) __builtin_amdgcn_global_load_lds( \
    (const __attribute__((address_space(1))) unsigned int*)(src), \
    (__attribute__((address_space(3))) unsigned int*)(dst), 16, 0, 0)

__device__ __forceinline__ float bf2f(u16 v) {
  union { unsigned int u; float f; } x; x.u = ((unsigned int)v) << 16; return x.f;
}
__device__ __forceinline__ u16 f2bf(float f) {
  union { float f; unsigned int u; } x; x.f = f;
  unsigned int lsb = (x.u >> 16) & 1u;
  return (u16)((x.u + 0x7fffu + lsb) >> 16);
}
// GELU tanh-form: gelu(x) = x * (1 - 1/(1 + 2^(c1*x + c2*x^3)))
__device__ __forceinline__ float gelu_f(float x) {
  float u = x * x;
  float w = x * (2.3023879925f + 0.1029517046f * u);
  float e = exp2f(w);
  float r = __builtin_amdgcn_rcpf(1.f + e);
  return x - x * r;
}

// ---------------------------------------------------------------------------
// General GEMM: C[m,n] = act( sum_k A[m,k]*Bt[n,k] + bias[n] )
// m97 structure, 128x128 tile, BK=64, DMA quad-XOR swizzle.
// XCD supertile swizzle when mtiles%8==0.
// MODE 0: A=A0. MODE 1: K-concat at SEL. MODE 2: N-switch at SEL (QKV).
// ACT 1: gelu. SPLITK 1: fp32 atomicAdd into Cf, scaled by 1/bias[bz*N+col].
// ---------------------------------------------------------------------------
template<int MODE, int ACT, int SPLITK>
__launch_bounds__(256, 2)
__global__ void gemm_abt(const u16* __restrict__ A0, const u16* __restrict__ A1,
                         int SEL, int lda,
                         const u16* __restrict__ Bt,
                         const float* __restrict__ bias,
                         u16* __restrict__ Cb, float* __restrict__ Cf,
                         int M, int N, int K,
                         long sAb, long sBb, long sCb)
{
  __shared__ __align__(16) u16 As[2 * 128 * 32];
  __shared__ __align__(16) u16 Bs[2 * 128 * 32];

  const int mtiles = M >> 7, ntiles = N >> 7;
  const int tile = blockIdx.x;
  int mt0, nt0;
  if ((mtiles & 7) == 0) {
    const int x = tile & 7, g = tile >> 3;
    mt0 = ((x * (mtiles >> 3)) + g / ntiles) << 7;
    nt0 = (g % ntiles) << 7;
  } else {
    mt0 = (tile % mtiles) << 7;
    nt0 = (tile / mtiles) << 7;
  }
  const int kchunk = K / (int)gridDim.y;
  const int k0beg = blockIdx.y * kchunk;
  const int k0end = k0beg + kchunk;
  const int bz = blockIdx.z;
  A0 += (long)bz * sAb;  A1 += (long)bz * sAb;  Bt += (long)bz * sBb;

  const u16* Abase = (MODE == 2 && nt0 >= SEL) ? A1 : A0;

  const int tid  = threadIdx.x;
  const int wave = tid >> 6, lane = tid & 63;
  const int srow = lane >> 2;
  const int gq   = (lane & 3) ^ (srow & 3);
  const int frow = lane & 15;
  const int fq   = lane >> 4;
  const int fqx  = (fq ^ (frow & 3)) * 8;

  f32x4 zero = {0.f, 0.f, 0.f, 0.f};
  f32x4 acc[4][4];
#pragma unroll
  for (int i = 0; i < 4; i++)
#pragma unroll
    for (int j = 0; j < 4; j++) acc[i][j] = zero;

  const int wm = (wave & 1) * 64, wn = (wave >> 1) * 64;

  for (int k0 = k0beg; k0 < k0end; k0 += 64) {
    __syncthreads();
    const u16* Asrc;
    int ka;
    if (MODE == 1) {
      const bool lo = (k0 < SEL);
      Asrc = lo ? A0 : A1;
      ka = lo ? k0 : (k0 - SEL);
    } else { Asrc = Abase; ka = k0; }
#pragma unroll
    for (int h = 0; h < 2; h++) {
#pragma unroll
      for (int i = 0; i < 2; i++) {
        const int chunk = i * 4 + wave;
        GLDS(&As[h * 4096 + chunk * 512],
             Asrc + (long)(mt0 + chunk * 16 + srow) * lda + (ka + h * 32 + gq * 8));
        GLDS(&Bs[h * 4096 + chunk * 512],
             Bt + (long)(nt0 + chunk * 16 + srow) * K + (k0 + h * 32 + gq * 8));
      }
    }
    __syncthreads();
#pragma unroll
    for (int h = 0; h < 2; h++) {
      short8 af[4], bf[4];
#pragma unroll
      for (int t = 0; t < 4; t++)
        af[t] = *(const short8*)&As[h * 4096 + (wm + t * 16 + frow) * 32 + fqx];
#pragma unroll
      for (int t = 0; t < 4; t++)
        bf[t] = *(const short8*)&Bs[h * 4096 + (wn + t * 16 + frow) * 32 + fqx];
#pragma unroll
      for (int mt = 0; mt < 4; mt++)
#pragma unroll
        for (int nt = 0; nt < 4; nt++)
          acc[mt][nt] = __builtin_amdgcn_mfma_f32_16x16x32_bf16(af[mt], bf[nt], acc[mt][nt], 0, 0, 0);
    }
  }

  if (SPLITK) {
    float* Cp = Cf + (long)bz * sCb;
    float sv[4];
#pragma unroll
    for (int nt = 0; nt < 4; nt++)
      sv[nt] = bias ? (1.f / bias[(long)bz * N + nt0 + wn + nt * 16 + frow]) : 1.f;
#pragma unroll
    for (int mt = 0; mt < 4; mt++)
#pragma unroll
      for (int r = 0; r < 4; r++) {
        const int row = mt0 + wm + mt * 16 + fq * 4 + r;
#pragma unroll
        for (int nt = 0; nt < 4; nt++)
          atomicAdd(&Cp[(long)row * N + nt0 + wn + nt * 16 + frow],
                    acc[mt][nt][r] * sv[nt]);
      }
  } else {
    u16* Cp = Cb + (long)bz * sCb;
    float bv[4];
#pragma unroll
    for (int nt = 0; nt < 4; nt++)
      bv[nt] = bias ? bias[nt0 + wn + nt * 16 + frow] : 0.f;
#pragma unroll
    for (int mt = 0; mt < 4; mt++)
#pragma unroll
      for (int r = 0; r < 4; r++) {
        const int row = mt0 + wm + mt * 16 + fq * 4 + r;
#pragma unroll
        for (int nt = 0; nt < 4; nt++) {
          float v = acc[mt][nt][r] + bv[nt];
          if (ACT == 1) v = gelu_f(v);
          Cp[(long)row * N + nt0 + wn + nt * 16 + frow] = f2bf(v);
        }
      }
  }
}

// ---------------------------------------------------------------------------
// GEMM (M-tile 64, full N=256) + fused LayerNorm epilogue.
// CVTB=1: B operand is fp32 (converted during LDS staging).
// OUTF=0: out bf16 (message=LN1). OUTF=1: +bias, LN2, +fp32 src residual,
// fp32 out (final FFN2).  z = gm0 >> zshift selects batch for A/B strides.
// ---------------------------------------------------------------------------
template<int CVTB, int OUTF>
__launch_bounds__(256, 3)
__global__ void gemm_ln(const u16* __restrict__ A, long sAb, int lda, int K,
                        const void* __restrict__ Btv, long sBb, int zshift,
                        const float* __restrict__ bias,
                        const float* __restrict__ gamma, const float* __restrict__ beta,
                        const float* __restrict__ src, void* __restrict__ outv,
                        long Moff)
{
  __shared__ __align__(16) u16 As[2 * 64 * 32];    // 8 KB
  __shared__ __align__(16) u16 Bs[2 * 256 * 32];   // 32 KB
  __shared__ float red_s[64][4], red_q[64][4];

  const int gm0 = blockIdx.x * 64;
  const int z = gm0 >> zshift;
  const int ml = gm0 - (z << zshift);
  A += (long)z * sAb + (long)ml * lda;
  const float* Bf = (const float*)Btv + (CVTB ? (long)z * sBb : 0);
  const u16*   Bb = (const u16*)Btv   + (CVTB ? 0 : (long)z * sBb);

  const int tid = threadIdx.x, wave = tid >> 6, lane = tid & 63;
  const int srow = lane >> 2, gq = (lane & 3) ^ (srow & 3);
  const int frow = lane & 15, fq = lane >> 4;
  const int fqx = (fq ^ (frow & 3)) * 8;
  const int wn = wave * 64;

  f32x4 zero = {0.f, 0.f, 0.f, 0.f};
  f32x4 acc[4][4];
#pragma unroll
  for (int i = 0; i < 4; i++)
#pragma unroll
    for (int j = 0; j < 4; j++) acc[i][j] = zero;

  for (int k0 = 0; k0 < K; k0 += 64) {
    __syncthreads();
#pragma unroll
    for (int h = 0; h < 2; h++) {
      GLDS(&As[h * 2048 + wave * 512],
           A + (long)(wave * 16 + srow) * lda + (k0 + h * 32 + gq * 8));
#pragma unroll
      for (int i = 0; i < 4; i++) {
        const int chunk = i * 4 + wave;
        if (CVTB) {
          const float* bp = Bf + (long)(chunk * 16 + srow) * K + (k0 + h * 32 + gq * 8);
          float4 p0 = *(const float4*)bp;
          float4 p1 = *(const float4*)(bp + 4);
          short8 w;
          w[0] = (short)f2bf(p0.x); w[1] = (short)f2bf(p0.y);
          w[2] = (short)f2bf(p0.z); w[3] = (short)f2bf(p0.w);
          w[4] = (short)f2bf(p1.x); w[5] = (short)f2bf(p1.y);
          w[6] = (short)f2bf(p1.z); w[7] = (short)f2bf(p1.w);
          *(short8*)&Bs[h * 8192 + chunk * 512 + srow * 32 + (lane & 3) * 8] = w;
        } else {
          GLDS(&Bs[h * 8192 + chunk * 512],
               Bb + (long)(chunk * 16 + srow) * K + (k0 + h * 32 + gq * 8));
        }
      }
    }
    __syncthreads();
#pragma unroll
    for (int h = 0; h < 2; h++) {
      short8 af[4], bf[4];
#pragma unroll
      for (int t = 0; t < 4; t++)
        af[t] = *(const short8*)&As[h * 2048 + (t * 16 + frow) * 32 + fqx];
#pragma unroll
      for (int t = 0; t < 4; t++)
        bf[t] = *(const short8*)&Bs[h * 8192 + (wn + t * 16 + frow) * 32 + fqx];
#pragma unroll
      for (int mt = 0; mt < 4; mt++)
#pragma unroll
        for (int nt = 0; nt < 4; nt++)
          acc[mt][nt] = __builtin_amdgcn_mfma_f32_16x16x32_bf16(af[mt], bf[nt], acc[mt][nt], 0, 0, 0);
    }
  }

  // LN epilogue over the 256 cols of each of the 64 rows.
  float gv[4], bv[4], b2v[4];
#pragma unroll
  for (int nt = 0; nt < 4; nt++) {
    const int col = wn + nt * 16 + frow;
    gv[nt] = gamma[col]; bv[nt] = beta[col];
    b2v[nt] = OUTF ? bias[col] : 0.f;
  }
#pragma unroll
  for (int mt = 0; mt < 4; mt++)
#pragma unroll
    for (int r = 0; r < 4; r++) {
      float s = 0.f, q = 0.f;
#pragma unroll
      for (int nt = 0; nt < 4; nt++) {
        float v = acc[mt][nt][r] + b2v[nt];
        acc[mt][nt][r] = v; s += v; q += v * v;
      }
#pragma unroll
      for (int m = 1; m < 16; m <<= 1) {
        s += __shfl_xor(s, m, 16); q += __shfl_xor(q, m, 16);
      }
      if (frow == 0) {
        const int row = mt * 16 + fq * 4 + r;
        red_s[row][wave] = s; red_q[row][wave] = q;
      }
    }
  __syncthreads();
#pragma unroll
  for (int mt = 0; mt < 4; mt++)
#pragma unroll
    for (int r = 0; r < 4; r++) {
      const int row = mt * 16 + fq * 4 + r;
      float4 ss = *(const float4*)red_s[row];
      float4 qq = *(const float4*)red_q[row];
      const float s = ss.x + ss.y + ss.z + ss.w;
      const float q = qq.x + qq.y + qq.z + qq.w;
      const float mu = s * (1.f / 256.f);
      const float var = q * (1.f / 256.f) - mu * mu;
      const float rs = 1.f / sqrtf(var + EPS_);
      const long grow = Moff + gm0 + row;
#pragma unroll
      for (int nt = 0; nt < 4; nt++) {
        const int col = wn + nt * 16 + frow;
        const float o = (acc[mt][nt][r] - mu) * rs * gv[nt] + bv[nt];
        if (OUTF)
          ((float*)outv)[grow * 256 + col] = o + src[grow * 256 + col];
        else
          ((u16*)outv)[grow * 256 + col] = f2bf(o);
      }
    }
}

// ---------------------------------------------------------------------------
// All weight packing in one launch (1792 blocks of (32,8)).
// ---------------------------------------------------------------------------
__global__ void weightpack(const float* __restrict__ Wq, const float* __restrict__ Wk,
                           const float* __restrict__ Wv, const float* __restrict__ Wl,
                           const float* __restrict__ W1, const float* __restrict__ W2,
                           u16* __restrict__ WqC, u16* __restrict__ WlT,
                           u16* __restrict__ WqkvT, u16* __restrict__ W1T,
                           u16* __restrict__ W2T)
{
  __shared__ u16 t[32][33];
  const int bid = blockIdx.x, tx = threadIdx.x, ty = threadIdx.y;
  const float* in; u16* out; int Cc, R, bx, by;
  if (bid < 256) {
    const int w = bid >> 6, tt = bid & 63;
    bx = (tt & 7) * 32; by = (tt >> 3) * 32; Cc = 256; R = 256;
    if (w == 0) {
#pragma unroll
      for (int i = ty; i < 32; i += 8)
        WqC[(long)(by + i) * 256 + bx + tx] = f2bf(Wq[(long)(by + i) * 256 + bx + tx]);
      return;
    }
    in  = (w == 1) ? Wl : (w == 2) ? Wk : Wv;
    out = (w == 1) ? WlT : (w == 2) ? (WqkvT + 65536) : (WqkvT + 131072);
  } else if (bid < 1280) {
    const int l = bid - 256; bx = (l & 63) * 32; by = (l >> 6) * 32;
    in = W1; out = W1T; Cc = 2048; R = 512;
  } else {
    const int l = bid - 1280; bx = (l & 7) * 32; by = (l >> 3) * 32;
    in = W2; out = W2T; Cc = 256; R = 2048;
  }
#pragma unroll
  for (int i = ty; i < 32; i += 8)
    t[i][tx] = f2bf(in[(long)(by + i) * Cc + bx + tx]);
  __syncthreads();
#pragma unroll
  for (int i = ty; i < 32; i += 8)
    out[(long)(bx + i) * R + by + tx] = t[tx][i];
}

// cast source/target fp32->bf16 (grid.y selects) + zero Mtf (tail blocks)
__global__ void castzero(const float* __restrict__ src, const float* __restrict__ tgt,
                         u16* __restrict__ srcB, u16* __restrict__ tgtB,
                         float* __restrict__ Mtf)
{
  const int x = blockIdx.x;
  if (x < BLC_ / 1024) {
    const float* in = blockIdx.y ? tgt : src;
    u16* out = blockIdx.y ? tgtB : srcB;
    const int i = (x * 256 + threadIdx.x) * 4;
    float4 v = *(const float4*)(in + i);
    ushort4 o; o.x = f2bf(v.x); o.y = f2bf(v.y); o.z = f2bf(v.z); o.w = f2bf(v.w);
    *(ushort4*)(out + i) = o;
  } else if (blockIdx.y == 0) {
    const int i = ((x - BLC_ / 1024) * 256 + threadIdx.x) * 4;
    float4 zv = {0.f, 0.f, 0.f, 0.f};
    *(float4*)(Mtf + i) = zv;
  }
}

// ql,k slices of QKV (B,L,768) -> (B,C,L). z<4: ql batches.
// z>=4: k batches with exp() applied (no max-sub: |k| small). NO atomics.
__global__ void transQK(const u16* __restrict__ QKV,
                        u16* __restrict__ qlT, u16* __restrict__ kT)
{
  __shared__ u16 t[32][33];
  const int z = blockIdx.z, zb = z & 3;
  const bool isk = (z >= 4);
  const u16* in = QKV + (long)zb * L_ * 768 + (isk ? 256 : 0);
  u16* out = (isk ? kT : qlT) + (long)zb * L_ * C_;
  const int bx = blockIdx.x * 32, by = blockIdx.y * 32;
  const int tx = threadIdx.x, ty = threadIdx.y;
#pragma unroll
  for (int i = ty; i < 32; i += 8)
    t[i][tx] = in[(long)(by + i) * 768 + bx + tx];
  __syncthreads();
  if (isk) {
#pragma unroll
    for (int i = ty; i < 32; i += 8)
      out[(long)(bx + i) * L_ + by + tx] = f2bf(__expf(bf2f(t[tx][i])));
  } else {
#pragma unroll
    for (int i = ty; i < 32; i += 8)
      out[(long)(bx + i) * L_ + by + tx] = t[tx][i];
  }
}

// sexp[r] = sum_n kT[r*L + n]  (r = b*C + e; contiguous rows, no atomics)
__global__ void colsum(const u16* __restrict__ kT, float* __restrict__ sexp)
{
  const long base = (long)blockIdx.x * L_;
  const int tid = threadIdx.x, wave = tid >> 6, lane = tid & 63;
  __shared__ float red[4];
  float s = 0.f;
#pragma unroll
  for (int it = 0; it < 4; it++) {
    short8 v = *(const short8*)&kT[base + (it * 256 + tid) * 8];
#pragma unroll
    for (int j = 0; j < 8; j++) s += bf2f((u16)v[j]);
  }
#pragma unroll
  for (int off = 32; off; off >>= 1) s += __shfl_xor(s, off, 64);
  if (lane == 0) red[wave] = s;
  __syncthreads();
  if (tid == 0) sexp[blockIdx.x] = red[0] + red[1] + red[2] + red[3];
}

// ---------------------------------------------------------------------------
extern "C" void kernel_launch(void* const* d_in, const int* in_sizes, int n_in,
                              void* d_out, int out_size, void* d_ws, size_t ws_size,
                              hipStream_t stream)
{
  const float* source = (const float*)d_in[0];
  const float* target = (const float*)d_in[1];
  const float* Wq     = (const float*)d_in[2];
  const float* Wk     = (const float*)d_in[3];
  const float* Wv     = (const float*)d_in[4];
  const float* Wl     = (const float*)d_in[5];
  const float* gamma1 = (const float*)d_in[6];
  const float* beta1  = (const float*)d_in[7];
  const float* W1     = (const float*)d_in[8];
  const float* b1     = (const float*)d_in[9];
  const float* W2     = (const float*)d_in[10];
  const float* b2     = (const float*)d_in[11];
  const float* gamma2 = (const float*)d_in[12];
  const float* beta2  = (const float*)d_in[13];
  (void)in_sizes; (void)n_in; (void)out_size;

  char* ws = (char*)d_ws;
  size_t off = 0;
  auto take = [&](size_t bytes) -> char* {
    char* p = ws + off; off += (bytes + 255) & ~(size_t)255; return p;
  };
  // fixed region (live through FFN)
  u16*   WqkvT = (u16*)take((size_t)768 * C_ * 2);   // [ql|k|v] weights, NxK
  u16*   WqC   = (u16*)take((size_t)C_ * C_ * 2);    // Wq cast (d,e)
  u16*   WlT   = (u16*)take((size_t)C_ * C_ * 2);
  u16*   W1T   = (u16*)take((size_t)FFN_ * 512 * 2);
  u16*   W2T   = (u16*)take((size_t)C_ * FFN_ * 2);
  float* Mtf   = (float*)take((size_t)B_ * C_ * C_ * 4);
  float* sexp  = (float*)take((size_t)B_ * C_ * 4);
  u16*   srcB  = (u16*)take((size_t)BLC_ * 2);
  u16*   msg   = (u16*)take((size_t)BLC_ * 2);
  const size_t ubase = off;
  // pool region (dead before FFN; hidden overlays it)
  u16*   tgtB  = (u16*)take((size_t)BLC_ * 2);
  u16*   QKV   = (u16*)take((size_t)BL_ * 768 * 2);
  u16*   qlT   = (u16*)take((size_t)BLC_ * 2);
  u16*   kT    = (u16*)take((size_t)BLC_ * 2);
  const size_t pool = off - ubase;
  u16*   hidden = (u16*)(ws + ubase);

  int nchunk = 1;
  for (; nchunk < 8; nchunk <<= 1) {
    size_t hid = ((size_t)BL_ / nchunk) * FFN_ * 2;
    size_t need = ubase + (hid > pool ? hid : pool);
    if (need <= ws_size) break;
  }
  const int Mc = BL_ / nchunk;

  dim3 tb(32, 8);
  weightpack<<<1792, tb, 0, stream>>>(Wq, Wk, Wv, Wl, W1, W2, WqC, WlT, WqkvT, W1T, W2T);
  castzero<<<dim3(BLC_ / 1024 + (B_ * C_ * C_) / 1024, 2), 256, 0, stream>>>(
      source, target, srcB, tgtB, Mtf);

  // Wql^T[c,d] = sum_e Wl[e,c] * Wq[d,e]  -> q-slot of WqkvT (tiny GEMM)
  gemm_abt<0,0,0><<<4, 256, 0, stream>>>(
      WlT, WlT, 0, C_, WqC, nullptr, WqkvT, nullptr, C_, C_, C_, 0, 0, 0);

  // [ql|k|v] = [src|tgt|tgt] @ [Wql|Wk|Wv]   (N-switch at 256)
  gemm_abt<2,0,0><<<(BL_/128)*(768/128), 256, 0, stream>>>(
      srcB, tgtB, 256, C_, WqkvT, nullptr, QKV, nullptr, BL_, 768, C_, 0, 0, 0);

  // ql transpose; k transpose+exp (normalization deferred to Mt GEMM)
  transQK<<<dim3(8, L_/32, 8), tb, 0, stream>>>(QKV, qlT, kT);
  // sexp[b,e] = sum_n kexp  (no atomics)
  colsum<<<B_*C_, 256, 0, stream>>>(kT, sexp);

  // Mt[c,e] = (sum_n qlT[c,n] * kexpT[e,n]) / sexp[e]  (split-K, fp32 atomics)
  gemm_abt<0,0,1><<<dim3(4, 16, B_), 256, 0, stream>>>(
      qlT, qlT, 0, L_, kT, sexp, nullptr, Mtf, C_, C_, L_,
      (long)C_*L_, (long)C_*L_, (long)C_*C_);

  // message = LN1( v @ Mt^T )   (v strided in QKV; Mt staged fp32->bf16)
  gemm_ln<1,0><<<BL_/64, 256, 0, stream>>>(
      QKV + 512, (long)L_*768, 768, 256, Mtf, (long)C_*C_, 13,
      nullptr, gamma1, beta1, nullptr, msg, 0);

  // FFN: hidden = gelu([src|msg]@W1+b1); out = src + LN2(hidden@W2+b2)
  for (int ch = 0; ch < nchunk; ch++) {
    const long moff = (long)ch * Mc;
    gemm_abt<1,1,0><<<(Mc/128)*(FFN_/128), 256, 0, stream>>>(
        srcB + moff * C_, msg + moff * C_, 256, C_, W1T, b1, hidden, nullptr,
        Mc, FFN_, 512, 0, 0, 0);
    gemm_ln<0,1><<<Mc/64, 256, 0, stream>>>(
        hidden, 0, FFN_, FFN_, W2T, 0, 30,
        b2, gamma2, beta2, source, d_out, moff);
  }
}